// Round 20
// baseline (712.107 us; speedup 1.0000x reference)
//
#include <hip/hip_runtime.h>
#include <hip/hip_bf16.h>
#include <hip/hip_fp16.h>

// ---------------------------------------------------------------------------
// GraphSAGE distance estimator.
//   CSR build (both graphs batched): LDS bucket hist -> scan -> bucket-grouped
//   scatter of PACKED (src | dlocal<<17) ints -> per-bucket LDS counting sort
//   with LDS staging (contiguous flush) + parallel block scan.
//   Per layer: {Y,R} = x@{Wl,Wr} fused GEMM with f16 operands in LDS and
//   v_dot2_f32_f16 (2 MAC/instr, fp32 accum). 24KB LDS -> 4 blocks/CU.
//   Y,R stored BF16 (agg gather row = one 128B line, fully consumed).
//   agg: R17-exact wave/node body (32-deep gather, no LDS, no loops) but
//   1024-thr blocks (16 nodes/block) and state+goal BATCHED in one launch:
//   4x fewer blocks/launch tests the dispatch-churn hypothesis (R17 59% occ
//   at 25K x 1.1us blocks ~ CP dispatch limit; R18/R19 showed any per-wave
//   looping/staging loses more throughput than residency gains).
//   ALL pipeline stages batched over {state,goal}: 10 launches total.
//   H = relu(csr-mean(Y) + bl + R) fused into aggregate.
//   Pool: 8 partial blocks per graph -> final_mlp (thread j owns feature j).
// ---------------------------------------------------------------------------

#define NB    128    // dst buckets (pow2)
#define EPB   16384  // edges per grouping block
#define BWMAX 1024   // max nodes per bucket (LDS arrays in sort)
#define PP    8      // pool partials per graph
#define SRCB  17     // bits for src id in packed pair (N <= 131072)
#define SCAP  28672  // staged edges per bucket (112 KB LDS)

typedef _Float16 v2h __attribute__((ext_vector_type(2)));
union U2H { unsigned int u; v2h h; __half2 hh; };

static __device__ __forceinline__ unsigned int pack2(float a, float b) {
    U2H t; t.hh = __floats2half2_rn(a, b); return t.u;
}
static __device__ __forceinline__ float dot2(unsigned int x, unsigned int w, float acc) {
    U2H xa, wa; xa.u = x; wa.u = w;
    return __builtin_amdgcn_fdot2(xa.h, wa.h, acc, false);
}

// ---- CSR build (batched over both graphs) ----------------------------------

__global__ __launch_bounds__(256) void p1_hist(const int* __restrict__ dstS,
                                               const int* __restrict__ dstG,
                                               int* __restrict__ blkhist,
                                               int E, int bsh, int nblk) {
    const int g = blockIdx.x / nblk;
    const int blk = blockIdx.x % nblk;
    const int* __restrict__ dst = g ? dstG : dstS;
    __shared__ int h[NB];
    for (int i = threadIdx.x; i < NB; i += 256) h[i] = 0;
    __syncthreads();
    const int base = blk * EPB;
    for (int k = 0; k < EPB; k += 256) {
        const int e = base + k + threadIdx.x;
        if (e < E) atomicAdd(&h[dst[e] >> bsh], 1);
    }
    __syncthreads();
    for (int i = threadIdx.x; i < NB; i += 256)
        blkhist[((size_t)(g * nblk + blk)) * NB + i] = h[i];
}

__global__ __launch_bounds__(NB) void p1_scan(const int* __restrict__ blkhist,
                                              int* __restrict__ basem,
                                              int* __restrict__ bucket_base,
                                              int nblk) {
    __shared__ int lds[NB];
    const int g = blockIdx.x;
    const int* __restrict__ bh = blkhist + (size_t)g * nblk * NB;
    int* __restrict__ bm = basem + (size_t)g * nblk * NB;
    int* __restrict__ bb = bucket_base + (size_t)g * (NB + 1);
    const int b = threadIdx.x;
    int s = 0;
    int k = 0;
    for (; k + 8 <= nblk; k += 8) {
        int v[8];
        #pragma unroll
        for (int t = 0; t < 8; ++t) v[t] = bh[(size_t)(k + t) * NB + b];
        #pragma unroll
        for (int t = 0; t < 8; ++t) s += v[t];
    }
    for (; k < nblk; ++k) s += bh[(size_t)k * NB + b];
    lds[b] = s;
    __syncthreads();
    for (int off = 1; off < NB; off <<= 1) {
        int v = (b >= off) ? lds[b - off] : 0;
        __syncthreads();
        lds[b] += v;
        __syncthreads();
    }
    int run = lds[b] - s;  // exclusive prefix
    bb[b] = run;
    if (b == NB - 1) bb[NB] = run + s;
    k = 0;
    for (; k + 8 <= nblk; k += 8) {
        int c[8];
        #pragma unroll
        for (int t = 0; t < 8; ++t) c[t] = bh[(size_t)(k + t) * NB + b];
        #pragma unroll
        for (int t = 0; t < 8; ++t) {
            bm[(size_t)(k + t) * NB + b] = run;
            run += c[t];
        }
    }
    for (; k < nblk; ++k) {
        const int c = bh[(size_t)k * NB + b];
        bm[(size_t)k * NB + b] = run;
        run += c;
    }
}

__global__ __launch_bounds__(256) void p1_scatter(const int* __restrict__ eiS,
                                                  const int* __restrict__ eiG,
                                                  const int* __restrict__ basem,
                                                  int* __restrict__ pairs,
                                                  int E, int bsh, int nblk) {
    const int g = blockIdx.x / nblk;
    const int blk = blockIdx.x % nblk;
    const int* __restrict__ src = g ? eiG : eiS;
    const int* __restrict__ dst = src + E;
    int* __restrict__ pr = pairs + (size_t)g * E;
    const int bwm = (1 << bsh) - 1;
    __shared__ int cur[NB];
    for (int i = threadIdx.x; i < NB; i += 256)
        cur[i] = basem[((size_t)(g * nblk + blk)) * NB + i];
    __syncthreads();
    const int base = blk * EPB;
    for (int k = 0; k < EPB; k += 256) {
        const int e = base + k + threadIdx.x;
        if (e < E) {
            const int d = dst[e];
            const int s = src[e];
            const int p = atomicAdd(&cur[d >> bsh], 1);
            pr[p] = s | ((d & bwm) << SRCB);   // packed: src(17b) | dlocal(<=10b)
        }
    }
}

// Per-bucket counting sort with LDS staging + parallel block scan.
__global__ __launch_bounds__(512) void p2_sort(const int* __restrict__ pairs,
                                               const int* __restrict__ bucket_base,
                                               int* __restrict__ csr,
                                               int* __restrict__ row_start,
                                               int N, int E, int bsh) {
    __shared__ int stage[SCAP];   // 112 KB
    __shared__ int cnt[BWMAX];    // 4 KB
    __shared__ int off[BWMAX];    // 4 KB
    __shared__ int ws[512];       // 2 KB
    const int g = blockIdx.x / NB;
    const int b = blockIdx.x % NB;
    const int bw = 1 << bsh;
    const int lo = b * bw;
    int nn = N - lo;
    if (nn <= 0) return;
    if (nn > bw) nn = bw;
    const int* __restrict__ pr = pairs + (size_t)g * E;
    const int* __restrict__ bb = bucket_base + (size_t)g * (NB + 1);
    int* __restrict__ cs = csr + (size_t)g * E;
    int* __restrict__ rs = row_start + (size_t)g * (N + 1);
    const int tid = threadIdx.x;
    for (int i = tid; i < nn; i += 512) cnt[i] = 0;
    __syncthreads();
    const int e0 = bb[b];
    const int e1 = bb[b + 1];
    const int ne = e1 - e0;
    for (int e = e0 + tid; e < e1; e += 512)
        atomicAdd(&cnt[pr[e] >> SRCB], 1);
    __syncthreads();
    {
        const int i0 = 2 * tid, i1 = 2 * tid + 1;
        const int c0 = (i0 < nn) ? cnt[i0] : 0;
        const int c1 = (i1 < nn) ? cnt[i1] : 0;
        const int s = c0 + c1;
        ws[tid] = s;
        __syncthreads();
        for (int o = 1; o < 512; o <<= 1) {
            int v = (tid >= o) ? ws[tid - o] : 0;
            __syncthreads();
            ws[tid] += v;
            __syncthreads();
        }
        const int base = e0 + ws[tid] - s;  // exclusive
        if (i0 < nn) off[i0] = base;
        if (i1 < nn) off[i1] = base + c0;
    }
    __syncthreads();
    for (int i = tid; i < nn; i += 512) {
        rs[lo + i] = off[i];
        cnt[i] = off[i];  // reuse as cursor
    }
    if (lo + nn == N && tid == 0) rs[N] = e1;
    __syncthreads();
    if (ne <= SCAP) {
        for (int e = e0 + tid; e < e1; e += 512) {
            const int v = pr[e];
            const int pos = atomicAdd(&cnt[v >> SRCB], 1);
            stage[pos - e0] = v & ((1 << SRCB) - 1);
        }
        __syncthreads();
        for (int i = tid; i < ne; i += 512) cs[e0 + i] = stage[i];
    } else {
        for (int e = e0 + tid; e < e1; e += 512) {
            const int v = pr[e];
            const int pos = atomicAdd(&cnt[v >> SRCB], 1);
            cs[pos] = v & ((1 << SRCB) - 1);
        }
    }
}

// ---- fused dual-weight GEMM, BATCHED over {state,goal} ----------------------
// Y(bf16) = x@Wl, R(bf16) = x@Wr; graph picked by blockIdx half.
template <int K>
__global__ __launch_bounds__(512) void gemm_fused(const float* __restrict__ xS,
                                                  const float* __restrict__ xG,
                                                  const float* __restrict__ WlS,
                                                  const float* __restrict__ WrS,
                                                  const float* __restrict__ WlG,
                                                  const float* __restrict__ WrG,
                                                  __hip_bfloat16* __restrict__ Y,
                                                  __hip_bfloat16* __restrict__ R,
                                                  int n, int nbg) {
    constexpr int KC = 64;
    constexpr int ROWS = 64;
    __shared__ uint4 ldsW4[(KC / 4) * 64];          // 16 KB
    __shared__ unsigned int ldsXu[ROWS * (KC / 2)]; // 8 KB
    const int g = (blockIdx.x >= nbg) ? 1 : 0;
    const int blk = blockIdx.x - g * nbg;
    const float* __restrict__ x  = g ? xG : xS;
    const float* __restrict__ Wl = g ? WlG : WlS;
    const float* __restrict__ Wr = g ? WrG : WrS;
    __hip_bfloat16* __restrict__ Yp = Y + (size_t)g * n * 64;
    __hip_bfloat16* __restrict__ Rp = R + (size_t)g * n * 64;
    const int tid = threadIdx.x;
    const int lane = tid & 63;
    const int wid = tid >> 6;
    const int rbase = blk * ROWS;

    float accY[8], accR[8];
    #pragma unroll
    for (int r = 0; r < 8; ++r) { accY[r] = 0.f; accR[r] = 0.f; }

    for (int k0 = 0; k0 < K; k0 += KC) {
        __syncthreads();
        for (int i = tid; i < (KC / 4) * 64; i += 512) {
            const int gp = i >> 6;
            const int c = i & 63;
            const int ka = k0 + gp * 4;
            const float wl0 = Wl[(size_t)ka * 64 + c],       wr0 = Wr[(size_t)ka * 64 + c];
            const float wl1 = Wl[(size_t)(ka + 1) * 64 + c], wr1 = Wr[(size_t)(ka + 1) * 64 + c];
            const float wl2 = Wl[(size_t)(ka + 2) * 64 + c], wr2 = Wr[(size_t)(ka + 2) * 64 + c];
            const float wl3 = Wl[(size_t)(ka + 3) * 64 + c], wr3 = Wr[(size_t)(ka + 3) * 64 + c];
            ldsW4[i] = make_uint4(pack2(wl0, wl1), pack2(wr0, wr1),
                                  pack2(wl2, wl3), pack2(wr2, wr3));
        }
        {
            constexpr int F4R = KC / 4;  // float4 per row = 16
            for (int i = tid; i < ROWS * F4R; i += 512) {
                const int rr = i / F4R;
                const int cc = i % F4R;
                int row = rbase + rr;
                if (row > n - 1) row = n - 1;
                const float4 xv = *(const float4*)(x + (size_t)row * K + k0 + cc * 4);
                ldsXu[rr * (KC / 2) + cc * 2 + 0] = pack2(xv.x, xv.y);
                ldsXu[rr * (KC / 2) + cc * 2 + 1] = pack2(xv.z, xv.w);
            }
        }
        __syncthreads();
        const int rw = wid * 8;
        #pragma unroll 2
        for (int k8 = 0; k8 < KC / 8; ++k8) {
            const uint4 w0 = ldsW4[(k8 * 2 + 0) * 64 + lane]; // k..k+3
            const uint4 w1 = ldsW4[(k8 * 2 + 1) * 64 + lane]; // k+4..k+7
            #pragma unroll
            for (int r = 0; r < 8; ++r) {
                const uint4 xq = *(const uint4*)(&ldsXu[(rw + r) * (KC / 2) + k8 * 4]);
                float yv = accY[r];
                float zv = accR[r];
                yv = dot2(xq.x, w0.x, yv);
                zv = dot2(xq.x, w0.y, zv);
                yv = dot2(xq.y, w0.z, yv);
                zv = dot2(xq.y, w0.w, zv);
                yv = dot2(xq.z, w1.x, yv);
                zv = dot2(xq.z, w1.y, zv);
                yv = dot2(xq.w, w1.z, yv);
                zv = dot2(xq.w, w1.w, zv);
                accY[r] = yv;
                accR[r] = zv;
            }
        }
    }
    #pragma unroll
    for (int r = 0; r < 8; ++r) {
        const int row = rbase + wid * 8 + r;
        if (row < n) {
            Yp[(size_t)row * 64 + lane] = __float2bfloat16(accY[r]);
            Rp[(size_t)row * 64 + lane] = __float2bfloat16(accR[r]);
        }
    }
}

// ---- aggregate + epilogue: H = relu(mean_csr(Y) + bl + R), BATCHED ----------
// R17-exact wave/node body; 1024 thr = 16 waves = 16 nodes/block (4x fewer
// blocks to dispatch); graph picked by blockIdx half.
__global__ __launch_bounds__(1024) void agg_fused(const __hip_bfloat16* __restrict__ Y,
                                                  const __hip_bfloat16* __restrict__ R,
                                                  const float* __restrict__ blS,
                                                  const float* __restrict__ blG,
                                                  const int* __restrict__ csr,
                                                  const int* __restrict__ row_start,
                                                  float* __restrict__ H,
                                                  int n, int E, int nbg) {
    const int g = (blockIdx.x >= nbg) ? 1 : 0;
    const int blk = blockIdx.x - g * nbg;
    const int wid = threadIdx.x >> 6;
    const int lane = threadIdx.x & 63;
    const int i = blk * 16 + wid;
    if (i >= n) return;
    const int* __restrict__ rs = row_start + (size_t)g * (n + 1);
    const int* __restrict__ cs = csr + (size_t)g * E;
    const __hip_bfloat16* __restrict__ Yp = Y + (size_t)g * n * 64;
    const __hip_bfloat16* __restrict__ Rp = R + (size_t)g * n * 64;
    const float* __restrict__ bl = g ? blG : blS;
    float* __restrict__ Hp = H + (size_t)g * n * 64;

    const int r0 = __builtin_amdgcn_readfirstlane(rs[i]);
    const int r1 = __builtin_amdgcn_readfirstlane(rs[i + 1]);
    float a[32];
    #pragma unroll
    for (int t = 0; t < 32; ++t) a[t] = 0.f;
    int e = r0;
    for (; e + 32 <= r1; e += 32) {
        #pragma unroll
        for (int t = 0; t < 32; ++t)
            a[t] += __bfloat162float(Yp[(size_t)cs[e + t] * 64 + lane]);
    }
    for (; e + 8 <= r1; e += 8) {
        #pragma unroll
        for (int t = 0; t < 8; ++t)
            a[t] += __bfloat162float(Yp[(size_t)cs[e + t] * 64 + lane]);
    }
    for (; e < r1; ++e) a[0] += __bfloat162float(Yp[(size_t)cs[e] * 64 + lane]);
    float acc = 0.f;
    #pragma unroll
    for (int t = 0; t < 32; ++t) acc += a[t];
    const int c = r1 - r0;
    const float sc = (c > 0) ? (1.0f / (float)c) : 1.0f;
    const float v = acc * sc + bl[lane] + __bfloat162float(Rp[(size_t)i * 64 + lane]);
    Hp[(size_t)i * 64 + lane] = fmaxf(v, 0.0f);
}

// ---- pooling: PP partial blocks per graph, BATCHED --------------------------
__global__ __launch_bounds__(256) void pool_part(const float* __restrict__ H,
                                                 const int* __restrict__ batchS,
                                                 const int* __restrict__ batchG,
                                                 float* __restrict__ partsS,
                                                 float* __restrict__ partsG,
                                                 int* __restrict__ cntS,
                                                 int* __restrict__ cntG,
                                                 int n, int nbg) {
    const int g = (blockIdx.x >= nbg) ? 1 : 0;
    const int blk = blockIdx.x - g * nbg;
    const int b = blk / PP;
    const int p = blk % PP;
    const int* __restrict__ batch = g ? batchG : batchS;
    const float* __restrict__ Hp = H + (size_t)g * n * 64;
    float* __restrict__ parts = g ? partsG : partsS;
    int* __restrict__ pcnt = g ? cntG : cntS;

    int lo = 0, hi = n;
    while (lo < hi) { int m = (lo + hi) >> 1; if (batch[m] < b) lo = m + 1; else hi = m; }
    const int beg = lo;
    hi = n;
    while (lo < hi) { int m = (lo + hi) >> 1; if (batch[m] < b + 1) lo = m + 1; else hi = m; }
    const int end = lo;
    const int len = end - beg;
    const int chunk = (len + PP - 1) / PP;
    const int s0 = beg + p * chunk;
    int s1 = s0 + chunk; if (s1 > end) s1 = end;

    const int wid = threadIdx.x >> 6;
    const int lane = threadIdx.x & 63;
    float acc = 0.f;
    for (int i = s0 + wid; i < s1; i += 4)
        acc += Hp[(size_t)i * 64 + lane];
    __shared__ float part[4][64];
    part[wid][lane] = acc;
    __syncthreads();
    if (wid == 0) {
        const float s = (part[0][lane] + part[1][lane]) + (part[2][lane] + part[3][lane]);
        parts[(size_t)(b * PP + p) * 64 + lane] = s;
        if (lane == 0 && p == 0) pcnt[b] = len;
    }
}

// ---- final MLP: one block per graph, thread j owns output feature j ---------
__global__ __launch_bounds__(64) void final_mlp(const float* __restrict__ partsS,
                                                const int* __restrict__ cntS,
                                                const float* __restrict__ partsG,
                                                const int* __restrict__ cntG,
                                                const float* __restrict__ depth,
                                                const float* __restrict__ W1,
                                                const float* __restrict__ b1,
                                                const float* __restrict__ W2,
                                                const float* __restrict__ b2,
                                                float* __restrict__ out, int Bn) {
    const int b = blockIdx.x;
    const int j = threadIdx.x;  // 0..63
    float dsum = 0.f;
    for (int i = j; i < Bn; i += 64) dsum += depth[i];
    #pragma unroll
    for (int o = 32; o > 0; o >>= 1) dsum += __shfl_xor(dsum, o);
    const float mean = dsum / (float)Bn;
    float dvar = 0.f;
    for (int i = j; i < Bn; i += 64) { const float t = depth[i] - mean; dvar = fmaf(t, t, dvar); }
    #pragma unroll
    for (int o = 32; o > 0; o >>= 1) dvar += __shfl_xor(dvar, o);
    const float stdv = sqrtf(dvar / (float)Bn);
    const float dn = (depth[b] - mean) / (stdv + 1e-6f);

    __shared__ float f[129];
    {
        float s = 0.f, g = 0.f;
        #pragma unroll
        for (int p = 0; p < PP; ++p) {
            s += partsS[(size_t)(b * PP + p) * 64 + j];
            g += partsG[(size_t)(b * PP + p) * 64 + j];
        }
        int cs = cntS[b]; if (cs < 1) cs = 1;
        int cg = cntG[b]; if (cg < 1) cg = 1;
        f[j] = s / (float)cs;
        f[64 + j] = g / (float)cg;
        if (j == 0) f[128] = dn;
    }
    __syncthreads();
    float acc = b1[j];
    #pragma unroll 8
    for (int k = 0; k < 129; ++k)
        acc = fmaf(f[k], W1[(size_t)k * 64 + j], acc);
    float o = fmaxf(acc, 0.0f) * W2[j];
    #pragma unroll
    for (int of = 32; of > 0; of >>= 1) o += __shfl_xor(o, of);
    if (j == 0) out[b] = o + b2[0];
}

extern "C" void kernel_launch(void* const* d_in, const int* in_sizes, int n_in,
                              void* d_out, int out_size, void* d_ws, size_t ws_size,
                              hipStream_t stream) {
    const float* state_x     = (const float*)d_in[0];
    const int*   state_ei    = (const int*)d_in[1];
    const int*   state_batch = (const int*)d_in[2];
    const float* goal_x      = (const float*)d_in[3];
    const int*   goal_ei     = (const int*)d_in[4];
    const int*   goal_batch  = (const int*)d_in[5];
    const float* depth       = (const float*)d_in[6];
    const float* s1_Wl = (const float*)d_in[7];
    const float* s1_bl = (const float*)d_in[8];
    const float* s1_Wr = (const float*)d_in[9];
    const float* s2_Wl = (const float*)d_in[10];
    const float* s2_bl = (const float*)d_in[11];
    const float* s2_Wr = (const float*)d_in[12];
    const float* g1_Wl = (const float*)d_in[13];
    const float* g1_bl = (const float*)d_in[14];
    const float* g1_Wr = (const float*)d_in[15];
    const float* g2_Wl = (const float*)d_in[16];
    const float* g2_bl = (const float*)d_in[17];
    const float* g2_Wr = (const float*)d_in[18];
    const float* mlp_W1 = (const float*)d_in[19];
    const float* mlp_b1 = (const float*)d_in[20];
    const float* mlp_W2 = (const float*)d_in[21];
    const float* mlp_b2 = (const float*)d_in[22];

    const int N  = in_sizes[0] / 128;
    const int E  = in_sizes[1] / 2;
    const int Bn = in_sizes[6];
    const int nblk = (E + EPB - 1) / EPB;
    int bsh = 0;
    while (((size_t)NB << bsh) < (size_t)N) ++bsh;  // bucket width 2^bsh

    char* w = (char*)d_ws;
    auto alloc = [&](size_t bytes) {
        char* p = w;
        w += (bytes + 255) & ~(size_t)255;
        return p;
    };
    char*  bufYraw     = alloc((size_t)2 * N * 64 * sizeof(__hip_bfloat16));  // both graphs; pairs alias
    char*  bufRraw     = alloc((size_t)2 * N * 64 * sizeof(__hip_bfloat16));
    float* bufH        = (float*)alloc((size_t)2 * N * 64 * sizeof(float));
    int*   csr         = (int*)alloc((size_t)2 * E * sizeof(int));
    int*   row_start   = (int*)alloc((size_t)2 * (N + 1) * sizeof(int));
    int*   blkhist     = (int*)alloc((size_t)2 * nblk * NB * sizeof(int));
    int*   basem       = (int*)alloc((size_t)2 * nblk * NB * sizeof(int));
    int*   bucket_base = (int*)alloc((size_t)2 * (NB + 1) * sizeof(int));
    float* partsS      = (float*)alloc((size_t)Bn * PP * 64 * sizeof(float));
    float* partsG      = (float*)alloc((size_t)Bn * PP * 64 * sizeof(float));
    int*   cntS        = (int*)alloc((size_t)Bn * sizeof(int));
    int*   cntG        = (int*)alloc((size_t)Bn * sizeof(int));
    __hip_bfloat16* bufY = (__hip_bfloat16*)bufYraw;
    __hip_bfloat16* bufR = (__hip_bfloat16*)bufRraw;
    int*   pairs       = (int*)bufYraw;  // packed pairs alias bufY (dead in CSR build)
    const size_t need = (size_t)(w - (char*)d_ws);
    const bool pairs_fit = (size_t)2 * E * sizeof(int) <= (size_t)2 * N * 64 * sizeof(__hip_bfloat16);
    if (need > ws_size || (1 << bsh) > BWMAX || !pairs_fit || N > (1 << SRCB)) {
        hipMemsetAsync(d_out, 0, (size_t)out_size * sizeof(float), stream);
        return;
    }

    // ---- CSR build, both graphs ----
    p1_hist<<<2 * nblk, 256, 0, stream>>>(state_ei + E, goal_ei + E, blkhist, E, bsh, nblk);
    p1_scan<<<2, NB, 0, stream>>>(blkhist, basem, bucket_base, nblk);
    p1_scatter<<<2 * nblk, 256, 0, stream>>>(state_ei, goal_ei, basem, pairs, E, bsh, nblk);
    p2_sort<<<2 * NB, 512, 0, stream>>>(pairs, bucket_base, csr, row_start, N, E, bsh);

    const int g64  = (N + 63) / 64;     // gemm blocks per graph
    const int g16  = (N + 15) / 16;     // agg blocks per graph (16 nodes/block)
    const int gpp  = Bn * PP;           // pool blocks per graph

    // ---- layer 1 (both graphs) ----
    gemm_fused<128><<<2 * g64, 512, 0, stream>>>(state_x, goal_x,
                                                 s1_Wl, s1_Wr, g1_Wl, g1_Wr,
                                                 bufY, bufR, N, g64);
    agg_fused<<<2 * g16, 1024, 0, stream>>>(bufY, bufR, s1_bl, g1_bl,
                                            csr, row_start, bufH, N, E, g16);
    // ---- layer 2 (both graphs) ----
    gemm_fused<64><<<2 * g64, 512, 0, stream>>>(bufH, bufH + (size_t)N * 64,
                                                s2_Wl, s2_Wr, g2_Wl, g2_Wr,
                                                bufY, bufR, N, g64);
    agg_fused<<<2 * g16, 1024, 0, stream>>>(bufY, bufR, s2_bl, g2_bl,
                                            csr, row_start, bufH, N, E, g16);
    // ---- pool (both graphs) ----
    pool_part<<<2 * gpp, 256, 0, stream>>>(bufH, state_batch, goal_batch,
                                           partsS, partsG, cntS, cntG, N, gpp);

    final_mlp<<<Bn, 64, 0, stream>>>(partsS, cntS, partsG, cntG, depth,
                                     mlp_W1, mlp_b1, mlp_W2, mlp_b2, (float*)d_out, Bn);
}

// Round 21
// 588.528 us; speedup vs baseline: 1.2100x; 1.2100x over previous
//
#include <hip/hip_runtime.h>
#include <hip/hip_bf16.h>
#include <hip/hip_fp16.h>

// ---------------------------------------------------------------------------
// GraphSAGE distance estimator.  (R17 structure; agg index path fixed.)
//   CSR build (both graphs batched): LDS bucket hist -> scan -> bucket-grouped
//   scatter of PACKED (src | dlocal<<17) ints -> per-bucket LDS counting sort
//   with LDS staging (contiguous flush) + parallel block scan.
//   Per layer: {Y,R} = x@{Wl,Wr} fused GEMM with f16 operands in LDS and
//   v_dot2_f32_f16 (2 MAC/instr, fp32 accum). 24KB LDS -> 4 blocks/CU.
//   Y,R stored BF16 (agg gather row = one 128B line, fully consumed).
//   agg: wave/node, 32-deep gather; csr indices loaded COALESCED once per
//   32-chunk and broadcast via v_readlane (R17-R20 analysis: the old
//   csr[e+t] uniform-address loads were 64-lane TA broadcasts, ~2x TA
//   pressure -- the same pathology as R6's x-loads).
//   H = relu(csr-mean(Y) + bl + R) fused into aggregate.
//   Pool: 8 partial blocks -> final_mlp (block/graph, thread j owns feature j).
// ---------------------------------------------------------------------------

#define NB    128    // dst buckets (pow2)
#define EPB   16384  // edges per grouping block
#define BWMAX 1024   // max nodes per bucket (LDS arrays in sort)
#define PP    8      // pool partials per graph
#define SRCB  17     // bits for src id in packed pair (N <= 131072)
#define SCAP  28672  // staged edges per bucket (112 KB LDS)

typedef _Float16 v2h __attribute__((ext_vector_type(2)));
union U2H { unsigned int u; v2h h; __half2 hh; };

static __device__ __forceinline__ unsigned int pack2(float a, float b) {
    U2H t; t.hh = __floats2half2_rn(a, b); return t.u;
}
static __device__ __forceinline__ float dot2(unsigned int x, unsigned int w, float acc) {
    U2H xa, wa; xa.u = x; wa.u = w;
    return __builtin_amdgcn_fdot2(xa.h, wa.h, acc, false);
}

// ---- CSR build (batched over both graphs) ----------------------------------

__global__ __launch_bounds__(256) void p1_hist(const int* __restrict__ dstS,
                                               const int* __restrict__ dstG,
                                               int* __restrict__ blkhist,
                                               int E, int bsh, int nblk) {
    const int g = blockIdx.x / nblk;
    const int blk = blockIdx.x % nblk;
    const int* __restrict__ dst = g ? dstG : dstS;
    __shared__ int h[NB];
    for (int i = threadIdx.x; i < NB; i += 256) h[i] = 0;
    __syncthreads();
    const int base = blk * EPB;
    for (int k = 0; k < EPB; k += 256) {
        const int e = base + k + threadIdx.x;
        if (e < E) atomicAdd(&h[dst[e] >> bsh], 1);
    }
    __syncthreads();
    for (int i = threadIdx.x; i < NB; i += 256)
        blkhist[((size_t)(g * nblk + blk)) * NB + i] = h[i];
}

__global__ __launch_bounds__(NB) void p1_scan(const int* __restrict__ blkhist,
                                              int* __restrict__ basem,
                                              int* __restrict__ bucket_base,
                                              int nblk) {
    __shared__ int lds[NB];
    const int g = blockIdx.x;
    const int* __restrict__ bh = blkhist + (size_t)g * nblk * NB;
    int* __restrict__ bm = basem + (size_t)g * nblk * NB;
    int* __restrict__ bb = bucket_base + (size_t)g * (NB + 1);
    const int b = threadIdx.x;
    int s = 0;
    int k = 0;
    for (; k + 8 <= nblk; k += 8) {
        int v[8];
        #pragma unroll
        for (int t = 0; t < 8; ++t) v[t] = bh[(size_t)(k + t) * NB + b];
        #pragma unroll
        for (int t = 0; t < 8; ++t) s += v[t];
    }
    for (; k < nblk; ++k) s += bh[(size_t)k * NB + b];
    lds[b] = s;
    __syncthreads();
    for (int off = 1; off < NB; off <<= 1) {
        int v = (b >= off) ? lds[b - off] : 0;
        __syncthreads();
        lds[b] += v;
        __syncthreads();
    }
    int run = lds[b] - s;  // exclusive prefix
    bb[b] = run;
    if (b == NB - 1) bb[NB] = run + s;
    k = 0;
    for (; k + 8 <= nblk; k += 8) {
        int c[8];
        #pragma unroll
        for (int t = 0; t < 8; ++t) c[t] = bh[(size_t)(k + t) * NB + b];
        #pragma unroll
        for (int t = 0; t < 8; ++t) {
            bm[(size_t)(k + t) * NB + b] = run;
            run += c[t];
        }
    }
    for (; k < nblk; ++k) {
        const int c = bh[(size_t)k * NB + b];
        bm[(size_t)k * NB + b] = run;
        run += c;
    }
}

__global__ __launch_bounds__(256) void p1_scatter(const int* __restrict__ eiS,
                                                  const int* __restrict__ eiG,
                                                  const int* __restrict__ basem,
                                                  int* __restrict__ pairs,
                                                  int E, int bsh, int nblk) {
    const int g = blockIdx.x / nblk;
    const int blk = blockIdx.x % nblk;
    const int* __restrict__ src = g ? eiG : eiS;
    const int* __restrict__ dst = src + E;
    int* __restrict__ pr = pairs + (size_t)g * E;
    const int bwm = (1 << bsh) - 1;
    __shared__ int cur[NB];
    for (int i = threadIdx.x; i < NB; i += 256)
        cur[i] = basem[((size_t)(g * nblk + blk)) * NB + i];
    __syncthreads();
    const int base = blk * EPB;
    for (int k = 0; k < EPB; k += 256) {
        const int e = base + k + threadIdx.x;
        if (e < E) {
            const int d = dst[e];
            const int s = src[e];
            const int p = atomicAdd(&cur[d >> bsh], 1);
            pr[p] = s | ((d & bwm) << SRCB);   // packed: src(17b) | dlocal(<=10b)
        }
    }
}

// Per-bucket counting sort with LDS staging + parallel block scan.
__global__ __launch_bounds__(512) void p2_sort(const int* __restrict__ pairs,
                                               const int* __restrict__ bucket_base,
                                               int* __restrict__ csr,
                                               int* __restrict__ row_start,
                                               int N, int E, int bsh) {
    __shared__ int stage[SCAP];   // 112 KB
    __shared__ int cnt[BWMAX];    // 4 KB
    __shared__ int off[BWMAX];    // 4 KB
    __shared__ int ws[512];       // 2 KB
    const int g = blockIdx.x / NB;
    const int b = blockIdx.x % NB;
    const int bw = 1 << bsh;
    const int lo = b * bw;
    int nn = N - lo;
    if (nn <= 0) return;
    if (nn > bw) nn = bw;
    const int* __restrict__ pr = pairs + (size_t)g * E;
    const int* __restrict__ bb = bucket_base + (size_t)g * (NB + 1);
    int* __restrict__ cs = csr + (size_t)g * E;
    int* __restrict__ rs = row_start + (size_t)g * (N + 1);
    const int tid = threadIdx.x;
    for (int i = tid; i < nn; i += 512) cnt[i] = 0;
    __syncthreads();
    const int e0 = bb[b];
    const int e1 = bb[b + 1];
    const int ne = e1 - e0;
    for (int e = e0 + tid; e < e1; e += 512)
        atomicAdd(&cnt[pr[e] >> SRCB], 1);
    __syncthreads();
    {
        const int i0 = 2 * tid, i1 = 2 * tid + 1;
        const int c0 = (i0 < nn) ? cnt[i0] : 0;
        const int c1 = (i1 < nn) ? cnt[i1] : 0;
        const int s = c0 + c1;
        ws[tid] = s;
        __syncthreads();
        for (int o = 1; o < 512; o <<= 1) {
            int v = (tid >= o) ? ws[tid - o] : 0;
            __syncthreads();
            ws[tid] += v;
            __syncthreads();
        }
        const int base = e0 + ws[tid] - s;  // exclusive
        if (i0 < nn) off[i0] = base;
        if (i1 < nn) off[i1] = base + c0;
    }
    __syncthreads();
    for (int i = tid; i < nn; i += 512) {
        rs[lo + i] = off[i];
        cnt[i] = off[i];  // reuse as cursor
    }
    if (lo + nn == N && tid == 0) rs[N] = e1;
    __syncthreads();
    if (ne <= SCAP) {
        for (int e = e0 + tid; e < e1; e += 512) {
            const int v = pr[e];
            const int pos = atomicAdd(&cnt[v >> SRCB], 1);
            stage[pos - e0] = v & ((1 << SRCB) - 1);
        }
        __syncthreads();
        for (int i = tid; i < ne; i += 512) cs[e0 + i] = stage[i];
    } else {
        for (int e = e0 + tid; e < e1; e += 512) {
            const int v = pr[e];
            const int pos = atomicAdd(&cnt[v >> SRCB], 1);
            cs[pos] = v & ((1 << SRCB) - 1);
        }
    }
}

// ---- fused dual-weight GEMM: Y(bf16) = x@Wl, R(bf16) = x@Wr -----------------
template <int K>
__global__ __launch_bounds__(512) void gemm_fused(const float* __restrict__ x,
                                                  const float* __restrict__ Wl,
                                                  const float* __restrict__ Wr,
                                                  __hip_bfloat16* __restrict__ Y,
                                                  __hip_bfloat16* __restrict__ R, int n) {
    constexpr int KC = 64;
    constexpr int ROWS = 64;
    __shared__ uint4 ldsW4[(KC / 4) * 64];          // 16 KB
    __shared__ unsigned int ldsXu[ROWS * (KC / 2)]; // 8 KB
    const int tid = threadIdx.x;
    const int lane = tid & 63;
    const int wid = tid >> 6;
    const int rbase = blockIdx.x * ROWS;

    float accY[8], accR[8];
    #pragma unroll
    for (int r = 0; r < 8; ++r) { accY[r] = 0.f; accR[r] = 0.f; }

    for (int k0 = 0; k0 < K; k0 += KC) {
        __syncthreads();
        for (int i = tid; i < (KC / 4) * 64; i += 512) {
            const int gp = i >> 6;
            const int c = i & 63;
            const int ka = k0 + gp * 4;
            const float wl0 = Wl[(size_t)ka * 64 + c],       wr0 = Wr[(size_t)ka * 64 + c];
            const float wl1 = Wl[(size_t)(ka + 1) * 64 + c], wr1 = Wr[(size_t)(ka + 1) * 64 + c];
            const float wl2 = Wl[(size_t)(ka + 2) * 64 + c], wr2 = Wr[(size_t)(ka + 2) * 64 + c];
            const float wl3 = Wl[(size_t)(ka + 3) * 64 + c], wr3 = Wr[(size_t)(ka + 3) * 64 + c];
            ldsW4[i] = make_uint4(pack2(wl0, wl1), pack2(wr0, wr1),
                                  pack2(wl2, wl3), pack2(wr2, wr3));
        }
        {
            constexpr int F4R = KC / 4;  // float4 per row = 16
            for (int i = tid; i < ROWS * F4R; i += 512) {
                const int rr = i / F4R;
                const int cc = i % F4R;
                int row = rbase + rr;
                if (row > n - 1) row = n - 1;
                const float4 xv = *(const float4*)(x + (size_t)row * K + k0 + cc * 4);
                ldsXu[rr * (KC / 2) + cc * 2 + 0] = pack2(xv.x, xv.y);
                ldsXu[rr * (KC / 2) + cc * 2 + 1] = pack2(xv.z, xv.w);
            }
        }
        __syncthreads();
        const int rw = wid * 8;
        #pragma unroll 2
        for (int k8 = 0; k8 < KC / 8; ++k8) {
            const uint4 w0 = ldsW4[(k8 * 2 + 0) * 64 + lane]; // k..k+3
            const uint4 w1 = ldsW4[(k8 * 2 + 1) * 64 + lane]; // k+4..k+7
            #pragma unroll
            for (int r = 0; r < 8; ++r) {
                const uint4 xq = *(const uint4*)(&ldsXu[(rw + r) * (KC / 2) + k8 * 4]);
                float yv = accY[r];
                float zv = accR[r];
                yv = dot2(xq.x, w0.x, yv);
                zv = dot2(xq.x, w0.y, zv);
                yv = dot2(xq.y, w0.z, yv);
                zv = dot2(xq.y, w0.w, zv);
                yv = dot2(xq.z, w1.x, yv);
                zv = dot2(xq.z, w1.y, zv);
                yv = dot2(xq.w, w1.z, yv);
                zv = dot2(xq.w, w1.w, zv);
                accY[r] = yv;
                accR[r] = zv;
            }
        }
    }
    #pragma unroll
    for (int r = 0; r < 8; ++r) {
        const int row = rbase + wid * 8 + r;
        if (row < n) {
            Y[(size_t)row * 64 + lane] = __float2bfloat16(accY[r]);
            R[(size_t)row * 64 + lane] = __float2bfloat16(accR[r]);
        }
    }
}

// ---- aggregate + epilogue: H = relu(mean_csr(Y) + bl + R) -------------------
// Wave per node. Main loop: 32 csr indices loaded with ONE coalesced vector
// load (lane&31), broadcast via v_readlane (SALU) -> 1 TA op per 32 indices
// instead of 32 same-address 64-lane broadcasts.
__global__ __launch_bounds__(256) void agg_fused(const __hip_bfloat16* __restrict__ Y,
                                                 const __hip_bfloat16* __restrict__ R,
                                                 const float* __restrict__ bl,
                                                 const int* __restrict__ csr,
                                                 const int* __restrict__ row_start,
                                                 float* __restrict__ H, int n) {
    const int wid = threadIdx.x >> 6;
    const int lane = threadIdx.x & 63;
    const int i = blockIdx.x * 4 + wid;
    if (i >= n) return;
    const int r0 = __builtin_amdgcn_readfirstlane(row_start[i]);
    const int r1 = __builtin_amdgcn_readfirstlane(row_start[i + 1]);
    float a[32];
    #pragma unroll
    for (int t = 0; t < 32; ++t) a[t] = 0.f;
    int e = r0;
    for (; e + 32 <= r1; e += 32) {
        const int myidx = csr[e + (lane & 31)];   // one coalesced index load
        #pragma unroll
        for (int t = 0; t < 32; ++t) {
            const int s = __builtin_amdgcn_readlane(myidx, t);
            a[t] += __bfloat162float(Y[(size_t)s * 64 + lane]);
        }
    }
    for (; e + 8 <= r1; e += 8) {
        #pragma unroll
        for (int t = 0; t < 8; ++t)
            a[t] += __bfloat162float(Y[(size_t)csr[e + t] * 64 + lane]);
    }
    for (; e < r1; ++e) a[0] += __bfloat162float(Y[(size_t)csr[e] * 64 + lane]);
    float acc = 0.f;
    #pragma unroll
    for (int t = 0; t < 32; ++t) acc += a[t];
    const int c = r1 - r0;
    const float sc = (c > 0) ? (1.0f / (float)c) : 1.0f;
    const float v = acc * sc + bl[lane] + __bfloat162float(R[(size_t)i * 64 + lane]);
    H[(size_t)i * 64 + lane] = fmaxf(v, 0.0f);
}

// ---- pooling: PP partial blocks per graph (sorted batch, binary search) -----
__global__ __launch_bounds__(256) void pool_part(const float* __restrict__ H,
                                                 const int* __restrict__ batch,
                                                 float* __restrict__ parts,
                                                 int* __restrict__ pcnt, int n) {
    const int b = blockIdx.x / PP;
    const int p = blockIdx.x % PP;
    int lo = 0, hi = n;
    while (lo < hi) { int m = (lo + hi) >> 1; if (batch[m] < b) lo = m + 1; else hi = m; }
    const int beg = lo;
    hi = n;
    while (lo < hi) { int m = (lo + hi) >> 1; if (batch[m] < b + 1) lo = m + 1; else hi = m; }
    const int end = lo;
    const int len = end - beg;
    const int chunk = (len + PP - 1) / PP;
    const int s0 = beg + p * chunk;
    int s1 = s0 + chunk; if (s1 > end) s1 = end;

    const int wid = threadIdx.x >> 6;
    const int lane = threadIdx.x & 63;
    float acc = 0.f;
    for (int i = s0 + wid; i < s1; i += 4)
        acc += H[(size_t)i * 64 + lane];
    __shared__ float part[4][64];
    part[wid][lane] = acc;
    __syncthreads();
    if (wid == 0) {
        const float s = (part[0][lane] + part[1][lane]) + (part[2][lane] + part[3][lane]);
        parts[(size_t)(b * PP + p) * 64 + lane] = s;
        if (lane == 0 && p == 0) pcnt[b] = len;
    }
}

// ---- final MLP: one block per graph, thread j owns output feature j ---------
__global__ __launch_bounds__(64) void final_mlp(const float* __restrict__ partsS,
                                                const int* __restrict__ cntS,
                                                const float* __restrict__ partsG,
                                                const int* __restrict__ cntG,
                                                const float* __restrict__ depth,
                                                const float* __restrict__ W1,
                                                const float* __restrict__ b1,
                                                const float* __restrict__ W2,
                                                const float* __restrict__ b2,
                                                float* __restrict__ out, int Bn) {
    const int b = blockIdx.x;
    const int j = threadIdx.x;  // 0..63
    float dsum = 0.f;
    for (int i = j; i < Bn; i += 64) dsum += depth[i];
    #pragma unroll
    for (int o = 32; o > 0; o >>= 1) dsum += __shfl_xor(dsum, o);
    const float mean = dsum / (float)Bn;
    float dvar = 0.f;
    for (int i = j; i < Bn; i += 64) { const float t = depth[i] - mean; dvar = fmaf(t, t, dvar); }
    #pragma unroll
    for (int o = 32; o > 0; o >>= 1) dvar += __shfl_xor(dvar, o);
    const float stdv = sqrtf(dvar / (float)Bn);
    const float dn = (depth[b] - mean) / (stdv + 1e-6f);

    __shared__ float f[129];
    {
        float s = 0.f, g = 0.f;
        #pragma unroll
        for (int p = 0; p < PP; ++p) {
            s += partsS[(size_t)(b * PP + p) * 64 + j];
            g += partsG[(size_t)(b * PP + p) * 64 + j];
        }
        int cs = cntS[b]; if (cs < 1) cs = 1;
        int cg = cntG[b]; if (cg < 1) cg = 1;
        f[j] = s / (float)cs;
        f[64 + j] = g / (float)cg;
        if (j == 0) f[128] = dn;
    }
    __syncthreads();
    float acc = b1[j];
    #pragma unroll 8
    for (int k = 0; k < 129; ++k)
        acc = fmaf(f[k], W1[(size_t)k * 64 + j], acc);
    float o = fmaxf(acc, 0.0f) * W2[j];
    #pragma unroll
    for (int of = 32; of > 0; of >>= 1) o += __shfl_xor(o, of);
    if (j == 0) out[b] = o + b2[0];
}

extern "C" void kernel_launch(void* const* d_in, const int* in_sizes, int n_in,
                              void* d_out, int out_size, void* d_ws, size_t ws_size,
                              hipStream_t stream) {
    const float* state_x     = (const float*)d_in[0];
    const int*   state_ei    = (const int*)d_in[1];
    const int*   state_batch = (const int*)d_in[2];
    const float* goal_x      = (const float*)d_in[3];
    const int*   goal_ei     = (const int*)d_in[4];
    const int*   goal_batch  = (const int*)d_in[5];
    const float* depth       = (const float*)d_in[6];
    const float* s1_Wl = (const float*)d_in[7];
    const float* s1_bl = (const float*)d_in[8];
    const float* s1_Wr = (const float*)d_in[9];
    const float* s2_Wl = (const float*)d_in[10];
    const float* s2_bl = (const float*)d_in[11];
    const float* s2_Wr = (const float*)d_in[12];
    const float* g1_Wl = (const float*)d_in[13];
    const float* g1_bl = (const float*)d_in[14];
    const float* g1_Wr = (const float*)d_in[15];
    const float* g2_Wl = (const float*)d_in[16];
    const float* g2_bl = (const float*)d_in[17];
    const float* g2_Wr = (const float*)d_in[18];
    const float* mlp_W1 = (const float*)d_in[19];
    const float* mlp_b1 = (const float*)d_in[20];
    const float* mlp_W2 = (const float*)d_in[21];
    const float* mlp_b2 = (const float*)d_in[22];

    const int N  = in_sizes[0] / 128;
    const int E  = in_sizes[1] / 2;
    const int Bn = in_sizes[6];
    const int nblk = (E + EPB - 1) / EPB;
    int bsh = 0;
    while (((size_t)NB << bsh) < (size_t)N) ++bsh;  // bucket width 2^bsh

    char* w = (char*)d_ws;
    auto alloc = [&](size_t bytes) {
        char* p = w;
        w += (bytes + 255) & ~(size_t)255;
        return p;
    };
    char*  bufYraw     = alloc((size_t)N * 64 * sizeof(float));  // bf16 Y + pairs alias
    char*  bufRraw     = alloc((size_t)N * 64 * sizeof(__hip_bfloat16));
    float* bufH        = (float*)alloc((size_t)N * 64 * sizeof(float));
    int*   csr         = (int*)alloc((size_t)2 * E * sizeof(int));
    int*   row_start   = (int*)alloc((size_t)2 * (N + 1) * sizeof(int));
    int*   blkhist     = (int*)alloc((size_t)2 * nblk * NB * sizeof(int));
    int*   basem       = (int*)alloc((size_t)2 * nblk * NB * sizeof(int));
    int*   bucket_base = (int*)alloc((size_t)2 * (NB + 1) * sizeof(int));
    float* partsS      = (float*)alloc((size_t)Bn * PP * 64 * sizeof(float));
    float* partsG      = (float*)alloc((size_t)Bn * PP * 64 * sizeof(float));
    int*   cntS        = (int*)alloc((size_t)Bn * sizeof(int));
    int*   cntG        = (int*)alloc((size_t)Bn * sizeof(int));
    __hip_bfloat16* bufY = (__hip_bfloat16*)bufYraw;
    __hip_bfloat16* bufR = (__hip_bfloat16*)bufRraw;
    int*   pairs       = (int*)bufYraw;  // packed pairs alias bufY (dead in CSR build)
    const size_t need = (size_t)(w - (char*)d_ws);
    const bool pairs_fit = (size_t)2 * E * sizeof(int) <= (size_t)N * 64 * sizeof(float);
    if (need > ws_size || (1 << bsh) > BWMAX || !pairs_fit || N > (1 << SRCB)) {
        hipMemsetAsync(d_out, 0, (size_t)out_size * sizeof(float), stream);
        return;
    }

    // ---- CSR build, both graphs ----
    p1_hist<<<2 * nblk, 256, 0, stream>>>(state_ei + E, goal_ei + E, blkhist, E, bsh, nblk);
    p1_scan<<<2, NB, 0, stream>>>(blkhist, basem, bucket_base, nblk);
    p1_scatter<<<2 * nblk, 256, 0, stream>>>(state_ei, goal_ei, basem, pairs, E, bsh, nblk);
    p2_sort<<<2 * NB, 512, 0, stream>>>(pairs, bucket_base, csr, row_start, N, E, bsh);

    const int g64 = (N + 63) / 64;
    const int g4  = (N + 3) / 4;
    const int* csrS = csr;
    const int* csrG = csr + E;
    const int* rsS  = row_start;
    const int* rsG  = row_start + (N + 1);

    // ---- state encoder ----
    gemm_fused<128><<<g64, 512, 0, stream>>>(state_x, s1_Wl, s1_Wr, bufY, bufR, N);
    agg_fused<<<g4, 256, 0, stream>>>(bufY, bufR, s1_bl, csrS, rsS, bufH, N);
    gemm_fused<64><<<g64, 512, 0, stream>>>(bufH, s2_Wl, s2_Wr, bufY, bufR, N);
    agg_fused<<<g4, 256, 0, stream>>>(bufY, bufR, s2_bl, csrS, rsS, bufH, N);
    pool_part<<<Bn * PP, 256, 0, stream>>>(bufH, state_batch, partsS, cntS, N);

    // ---- goal encoder ----
    gemm_fused<128><<<g64, 512, 0, stream>>>(goal_x, g1_Wl, g1_Wr, bufY, bufR, N);
    agg_fused<<<g4, 256, 0, stream>>>(bufY, bufR, g1_bl, csrG, rsG, bufH, N);
    gemm_fused<64><<<g64, 512, 0, stream>>>(bufH, g2_Wl, g2_Wr, bufY, bufR, N);
    agg_fused<<<g4, 256, 0, stream>>>(bufY, bufR, g2_bl, csrG, rsG, bufH, N);
    pool_part<<<Bn * PP, 256, 0, stream>>>(bufH, goal_batch, partsG, cntG, N);

    final_mlp<<<Bn, 64, 0, stream>>>(partsS, cntS, partsG, cntG, depth,
                                     mlp_W1, mlp_b1, mlp_W2, mlp_b2, (float*)d_out, Bn);
}

// Round 22
// 577.720 us; speedup vs baseline: 1.2326x; 1.0187x over previous
//
#include <hip/hip_runtime.h>
#include <hip/hip_bf16.h>
#include <hip/hip_fp16.h>

// ---------------------------------------------------------------------------
// GraphSAGE distance estimator.  (R17-exact configuration — best measured.)
//   CSR build (both graphs batched): LDS bucket hist -> scan -> bucket-grouped
//   scatter of PACKED (src | dlocal<<17) ints -> per-bucket LDS counting sort
//   with LDS staging (contiguous flush) + parallel block scan.
//   Per layer: {Y,R} = x@{Wl,Wr} fused GEMM with f16 operands in LDS and
//   v_dot2_f32_f16 (2 MAC/instr, fp32 accum). 24KB LDS -> 4 blocks/CU.
//   Y,R stored BF16 (agg gather row = one 128B line, fully consumed).
//   agg: wave/node, 32-deep gather pipeline (empirically pinned at ~71us
//   across 5 structural variants: LDS-staging, persistence, fat blocks,
//   coalesced+readlane indices all flat or worse -> memory-path floor).
//   H = relu(csr-mean(Y) + bl + R) fused into aggregate.
//   Pool: 8 partial blocks -> final_mlp (block/graph, thread j owns feature j).
// ---------------------------------------------------------------------------

#define NB    128    // dst buckets (pow2)
#define EPB   16384  // edges per grouping block
#define BWMAX 1024   // max nodes per bucket (LDS arrays in sort)
#define PP    8      // pool partials per graph
#define SRCB  17     // bits for src id in packed pair (N <= 131072)
#define SCAP  28672  // staged edges per bucket (112 KB LDS)

typedef _Float16 v2h __attribute__((ext_vector_type(2)));
union U2H { unsigned int u; v2h h; __half2 hh; };

static __device__ __forceinline__ unsigned int pack2(float a, float b) {
    U2H t; t.hh = __floats2half2_rn(a, b); return t.u;
}
static __device__ __forceinline__ float dot2(unsigned int x, unsigned int w, float acc) {
    U2H xa, wa; xa.u = x; wa.u = w;
    return __builtin_amdgcn_fdot2(xa.h, wa.h, acc, false);
}

// ---- CSR build (batched over both graphs) ----------------------------------

__global__ __launch_bounds__(256) void p1_hist(const int* __restrict__ dstS,
                                               const int* __restrict__ dstG,
                                               int* __restrict__ blkhist,
                                               int E, int bsh, int nblk) {
    const int g = blockIdx.x / nblk;
    const int blk = blockIdx.x % nblk;
    const int* __restrict__ dst = g ? dstG : dstS;
    __shared__ int h[NB];
    for (int i = threadIdx.x; i < NB; i += 256) h[i] = 0;
    __syncthreads();
    const int base = blk * EPB;
    for (int k = 0; k < EPB; k += 256) {
        const int e = base + k + threadIdx.x;
        if (e < E) atomicAdd(&h[dst[e] >> bsh], 1);
    }
    __syncthreads();
    for (int i = threadIdx.x; i < NB; i += 256)
        blkhist[((size_t)(g * nblk + blk)) * NB + i] = h[i];
}

__global__ __launch_bounds__(NB) void p1_scan(const int* __restrict__ blkhist,
                                              int* __restrict__ basem,
                                              int* __restrict__ bucket_base,
                                              int nblk) {
    __shared__ int lds[NB];
    const int g = blockIdx.x;
    const int* __restrict__ bh = blkhist + (size_t)g * nblk * NB;
    int* __restrict__ bm = basem + (size_t)g * nblk * NB;
    int* __restrict__ bb = bucket_base + (size_t)g * (NB + 1);
    const int b = threadIdx.x;
    int s = 0;
    int k = 0;
    for (; k + 8 <= nblk; k += 8) {
        int v[8];
        #pragma unroll
        for (int t = 0; t < 8; ++t) v[t] = bh[(size_t)(k + t) * NB + b];
        #pragma unroll
        for (int t = 0; t < 8; ++t) s += v[t];
    }
    for (; k < nblk; ++k) s += bh[(size_t)k * NB + b];
    lds[b] = s;
    __syncthreads();
    for (int off = 1; off < NB; off <<= 1) {
        int v = (b >= off) ? lds[b - off] : 0;
        __syncthreads();
        lds[b] += v;
        __syncthreads();
    }
    int run = lds[b] - s;  // exclusive prefix
    bb[b] = run;
    if (b == NB - 1) bb[NB] = run + s;
    k = 0;
    for (; k + 8 <= nblk; k += 8) {
        int c[8];
        #pragma unroll
        for (int t = 0; t < 8; ++t) c[t] = bh[(size_t)(k + t) * NB + b];
        #pragma unroll
        for (int t = 0; t < 8; ++t) {
            bm[(size_t)(k + t) * NB + b] = run;
            run += c[t];
        }
    }
    for (; k < nblk; ++k) {
        const int c = bh[(size_t)k * NB + b];
        bm[(size_t)k * NB + b] = run;
        run += c;
    }
}

__global__ __launch_bounds__(256) void p1_scatter(const int* __restrict__ eiS,
                                                  const int* __restrict__ eiG,
                                                  const int* __restrict__ basem,
                                                  int* __restrict__ pairs,
                                                  int E, int bsh, int nblk) {
    const int g = blockIdx.x / nblk;
    const int blk = blockIdx.x % nblk;
    const int* __restrict__ src = g ? eiG : eiS;
    const int* __restrict__ dst = src + E;
    int* __restrict__ pr = pairs + (size_t)g * E;
    const int bwm = (1 << bsh) - 1;
    __shared__ int cur[NB];
    for (int i = threadIdx.x; i < NB; i += 256)
        cur[i] = basem[((size_t)(g * nblk + blk)) * NB + i];
    __syncthreads();
    const int base = blk * EPB;
    for (int k = 0; k < EPB; k += 256) {
        const int e = base + k + threadIdx.x;
        if (e < E) {
            const int d = dst[e];
            const int s = src[e];
            const int p = atomicAdd(&cur[d >> bsh], 1);
            pr[p] = s | ((d & bwm) << SRCB);   // packed: src(17b) | dlocal(<=10b)
        }
    }
}

// Per-bucket counting sort with LDS staging + parallel block scan.
__global__ __launch_bounds__(512) void p2_sort(const int* __restrict__ pairs,
                                               const int* __restrict__ bucket_base,
                                               int* __restrict__ csr,
                                               int* __restrict__ row_start,
                                               int N, int E, int bsh) {
    __shared__ int stage[SCAP];   // 112 KB
    __shared__ int cnt[BWMAX];    // 4 KB
    __shared__ int off[BWMAX];    // 4 KB
    __shared__ int ws[512];       // 2 KB
    const int g = blockIdx.x / NB;
    const int b = blockIdx.x % NB;
    const int bw = 1 << bsh;
    const int lo = b * bw;
    int nn = N - lo;
    if (nn <= 0) return;
    if (nn > bw) nn = bw;
    const int* __restrict__ pr = pairs + (size_t)g * E;
    const int* __restrict__ bb = bucket_base + (size_t)g * (NB + 1);
    int* __restrict__ cs = csr + (size_t)g * E;
    int* __restrict__ rs = row_start + (size_t)g * (N + 1);
    const int tid = threadIdx.x;
    for (int i = tid; i < nn; i += 512) cnt[i] = 0;
    __syncthreads();
    const int e0 = bb[b];
    const int e1 = bb[b + 1];
    const int ne = e1 - e0;
    for (int e = e0 + tid; e < e1; e += 512)
        atomicAdd(&cnt[pr[e] >> SRCB], 1);
    __syncthreads();
    {
        const int i0 = 2 * tid, i1 = 2 * tid + 1;
        const int c0 = (i0 < nn) ? cnt[i0] : 0;
        const int c1 = (i1 < nn) ? cnt[i1] : 0;
        const int s = c0 + c1;
        ws[tid] = s;
        __syncthreads();
        for (int o = 1; o < 512; o <<= 1) {
            int v = (tid >= o) ? ws[tid - o] : 0;
            __syncthreads();
            ws[tid] += v;
            __syncthreads();
        }
        const int base = e0 + ws[tid] - s;  // exclusive
        if (i0 < nn) off[i0] = base;
        if (i1 < nn) off[i1] = base + c0;
    }
    __syncthreads();
    for (int i = tid; i < nn; i += 512) {
        rs[lo + i] = off[i];
        cnt[i] = off[i];  // reuse as cursor
    }
    if (lo + nn == N && tid == 0) rs[N] = e1;
    __syncthreads();
    if (ne <= SCAP) {
        for (int e = e0 + tid; e < e1; e += 512) {
            const int v = pr[e];
            const int pos = atomicAdd(&cnt[v >> SRCB], 1);
            stage[pos - e0] = v & ((1 << SRCB) - 1);
        }
        __syncthreads();
        for (int i = tid; i < ne; i += 512) cs[e0 + i] = stage[i];
    } else {
        for (int e = e0 + tid; e < e1; e += 512) {
            const int v = pr[e];
            const int pos = atomicAdd(&cnt[v >> SRCB], 1);
            cs[pos] = v & ((1 << SRCB) - 1);
        }
    }
}

// ---- fused dual-weight GEMM: Y(bf16) = x@Wl, R(bf16) = x@Wr -----------------
template <int K>
__global__ __launch_bounds__(512) void gemm_fused(const float* __restrict__ x,
                                                  const float* __restrict__ Wl,
                                                  const float* __restrict__ Wr,
                                                  __hip_bfloat16* __restrict__ Y,
                                                  __hip_bfloat16* __restrict__ R, int n) {
    constexpr int KC = 64;
    constexpr int ROWS = 64;
    __shared__ uint4 ldsW4[(KC / 4) * 64];          // 16 KB
    __shared__ unsigned int ldsXu[ROWS * (KC / 2)]; // 8 KB
    const int tid = threadIdx.x;
    const int lane = tid & 63;
    const int wid = tid >> 6;
    const int rbase = blockIdx.x * ROWS;

    float accY[8], accR[8];
    #pragma unroll
    for (int r = 0; r < 8; ++r) { accY[r] = 0.f; accR[r] = 0.f; }

    for (int k0 = 0; k0 < K; k0 += KC) {
        __syncthreads();
        for (int i = tid; i < (KC / 4) * 64; i += 512) {
            const int gp = i >> 6;
            const int c = i & 63;
            const int ka = k0 + gp * 4;
            const float wl0 = Wl[(size_t)ka * 64 + c],       wr0 = Wr[(size_t)ka * 64 + c];
            const float wl1 = Wl[(size_t)(ka + 1) * 64 + c], wr1 = Wr[(size_t)(ka + 1) * 64 + c];
            const float wl2 = Wl[(size_t)(ka + 2) * 64 + c], wr2 = Wr[(size_t)(ka + 2) * 64 + c];
            const float wl3 = Wl[(size_t)(ka + 3) * 64 + c], wr3 = Wr[(size_t)(ka + 3) * 64 + c];
            ldsW4[i] = make_uint4(pack2(wl0, wl1), pack2(wr0, wr1),
                                  pack2(wl2, wl3), pack2(wr2, wr3));
        }
        {
            constexpr int F4R = KC / 4;  // float4 per row = 16
            for (int i = tid; i < ROWS * F4R; i += 512) {
                const int rr = i / F4R;
                const int cc = i % F4R;
                int row = rbase + rr;
                if (row > n - 1) row = n - 1;
                const float4 xv = *(const float4*)(x + (size_t)row * K + k0 + cc * 4);
                ldsXu[rr * (KC / 2) + cc * 2 + 0] = pack2(xv.x, xv.y);
                ldsXu[rr * (KC / 2) + cc * 2 + 1] = pack2(xv.z, xv.w);
            }
        }
        __syncthreads();
        const int rw = wid * 8;
        #pragma unroll 2
        for (int k8 = 0; k8 < KC / 8; ++k8) {
            const uint4 w0 = ldsW4[(k8 * 2 + 0) * 64 + lane]; // k..k+3
            const uint4 w1 = ldsW4[(k8 * 2 + 1) * 64 + lane]; // k+4..k+7
            #pragma unroll
            for (int r = 0; r < 8; ++r) {
                const uint4 xq = *(const uint4*)(&ldsXu[(rw + r) * (KC / 2) + k8 * 4]);
                float yv = accY[r];
                float zv = accR[r];
                yv = dot2(xq.x, w0.x, yv);
                zv = dot2(xq.x, w0.y, zv);
                yv = dot2(xq.y, w0.z, yv);
                zv = dot2(xq.y, w0.w, zv);
                yv = dot2(xq.z, w1.x, yv);
                zv = dot2(xq.z, w1.y, zv);
                yv = dot2(xq.w, w1.z, yv);
                zv = dot2(xq.w, w1.w, zv);
                accY[r] = yv;
                accR[r] = zv;
            }
        }
    }
    #pragma unroll
    for (int r = 0; r < 8; ++r) {
        const int row = rbase + wid * 8 + r;
        if (row < n) {
            Y[(size_t)row * 64 + lane] = __float2bfloat16(accY[r]);
            R[(size_t)row * 64 + lane] = __float2bfloat16(accR[r]);
        }
    }
}

// ---- aggregate + epilogue: H = relu(mean_csr(Y) + bl + R) -------------------
__global__ __launch_bounds__(256) void agg_fused(const __hip_bfloat16* __restrict__ Y,
                                                 const __hip_bfloat16* __restrict__ R,
                                                 const float* __restrict__ bl,
                                                 const int* __restrict__ csr,
                                                 const int* __restrict__ row_start,
                                                 float* __restrict__ H, int n) {
    const int wid = threadIdx.x >> 6;
    const int lane = threadIdx.x & 63;
    const int i = blockIdx.x * 4 + wid;
    if (i >= n) return;
    const int r0 = __builtin_amdgcn_readfirstlane(row_start[i]);
    const int r1 = __builtin_amdgcn_readfirstlane(row_start[i + 1]);
    float a[32];
    #pragma unroll
    for (int t = 0; t < 32; ++t) a[t] = 0.f;
    int e = r0;
    for (; e + 32 <= r1; e += 32) {
        #pragma unroll
        for (int t = 0; t < 32; ++t)
            a[t] += __bfloat162float(Y[(size_t)csr[e + t] * 64 + lane]);
    }
    for (; e + 8 <= r1; e += 8) {
        #pragma unroll
        for (int t = 0; t < 8; ++t)
            a[t] += __bfloat162float(Y[(size_t)csr[e + t] * 64 + lane]);
    }
    for (; e < r1; ++e) a[0] += __bfloat162float(Y[(size_t)csr[e] * 64 + lane]);
    float acc = 0.f;
    #pragma unroll
    for (int t = 0; t < 32; ++t) acc += a[t];
    const int c = r1 - r0;
    const float sc = (c > 0) ? (1.0f / (float)c) : 1.0f;
    const float v = acc * sc + bl[lane] + __bfloat162float(R[(size_t)i * 64 + lane]);
    H[(size_t)i * 64 + lane] = fmaxf(v, 0.0f);
}

// ---- pooling: PP partial blocks per graph (sorted batch, binary search) -----
__global__ __launch_bounds__(256) void pool_part(const float* __restrict__ H,
                                                 const int* __restrict__ batch,
                                                 float* __restrict__ parts,
                                                 int* __restrict__ pcnt, int n) {
    const int b = blockIdx.x / PP;
    const int p = blockIdx.x % PP;
    int lo = 0, hi = n;
    while (lo < hi) { int m = (lo + hi) >> 1; if (batch[m] < b) lo = m + 1; else hi = m; }
    const int beg = lo;
    hi = n;
    while (lo < hi) { int m = (lo + hi) >> 1; if (batch[m] < b + 1) lo = m + 1; else hi = m; }
    const int end = lo;
    const int len = end - beg;
    const int chunk = (len + PP - 1) / PP;
    const int s0 = beg + p * chunk;
    int s1 = s0 + chunk; if (s1 > end) s1 = end;

    const int wid = threadIdx.x >> 6;
    const int lane = threadIdx.x & 63;
    float acc = 0.f;
    for (int i = s0 + wid; i < s1; i += 4)
        acc += H[(size_t)i * 64 + lane];
    __shared__ float part[4][64];
    part[wid][lane] = acc;
    __syncthreads();
    if (wid == 0) {
        const float s = (part[0][lane] + part[1][lane]) + (part[2][lane] + part[3][lane]);
        parts[(size_t)(b * PP + p) * 64 + lane] = s;
        if (lane == 0 && p == 0) pcnt[b] = len;
    }
}

// ---- final MLP: one block per graph, thread j owns output feature j ---------
__global__ __launch_bounds__(64) void final_mlp(const float* __restrict__ partsS,
                                                const int* __restrict__ cntS,
                                                const float* __restrict__ partsG,
                                                const int* __restrict__ cntG,
                                                const float* __restrict__ depth,
                                                const float* __restrict__ W1,
                                                const float* __restrict__ b1,
                                                const float* __restrict__ W2,
                                                const float* __restrict__ b2,
                                                float* __restrict__ out, int Bn) {
    const int b = blockIdx.x;
    const int j = threadIdx.x;  // 0..63
    float dsum = 0.f;
    for (int i = j; i < Bn; i += 64) dsum += depth[i];
    #pragma unroll
    for (int o = 32; o > 0; o >>= 1) dsum += __shfl_xor(dsum, o);
    const float mean = dsum / (float)Bn;
    float dvar = 0.f;
    for (int i = j; i < Bn; i += 64) { const float t = depth[i] - mean; dvar = fmaf(t, t, dvar); }
    #pragma unroll
    for (int o = 32; o > 0; o >>= 1) dvar += __shfl_xor(dvar, o);
    const float stdv = sqrtf(dvar / (float)Bn);
    const float dn = (depth[b] - mean) / (stdv + 1e-6f);

    __shared__ float f[129];
    {
        float s = 0.f, g = 0.f;
        #pragma unroll
        for (int p = 0; p < PP; ++p) {
            s += partsS[(size_t)(b * PP + p) * 64 + j];
            g += partsG[(size_t)(b * PP + p) * 64 + j];
        }
        int cs = cntS[b]; if (cs < 1) cs = 1;
        int cg = cntG[b]; if (cg < 1) cg = 1;
        f[j] = s / (float)cs;
        f[64 + j] = g / (float)cg;
        if (j == 0) f[128] = dn;
    }
    __syncthreads();
    float acc = b1[j];
    #pragma unroll 8
    for (int k = 0; k < 129; ++k)
        acc = fmaf(f[k], W1[(size_t)k * 64 + j], acc);
    float o = fmaxf(acc, 0.0f) * W2[j];
    #pragma unroll
    for (int of = 32; of > 0; of >>= 1) o += __shfl_xor(o, of);
    if (j == 0) out[b] = o + b2[0];
}

extern "C" void kernel_launch(void* const* d_in, const int* in_sizes, int n_in,
                              void* d_out, int out_size, void* d_ws, size_t ws_size,
                              hipStream_t stream) {
    const float* state_x     = (const float*)d_in[0];
    const int*   state_ei    = (const int*)d_in[1];
    const int*   state_batch = (const int*)d_in[2];
    const float* goal_x      = (const float*)d_in[3];
    const int*   goal_ei     = (const int*)d_in[4];
    const int*   goal_batch  = (const int*)d_in[5];
    const float* depth       = (const float*)d_in[6];
    const float* s1_Wl = (const float*)d_in[7];
    const float* s1_bl = (const float*)d_in[8];
    const float* s1_Wr = (const float*)d_in[9];
    const float* s2_Wl = (const float*)d_in[10];
    const float* s2_bl = (const float*)d_in[11];
    const float* s2_Wr = (const float*)d_in[12];
    const float* g1_Wl = (const float*)d_in[13];
    const float* g1_bl = (const float*)d_in[14];
    const float* g1_Wr = (const float*)d_in[15];
    const float* g2_Wl = (const float*)d_in[16];
    const float* g2_bl = (const float*)d_in[17];
    const float* g2_Wr = (const float*)d_in[18];
    const float* mlp_W1 = (const float*)d_in[19];
    const float* mlp_b1 = (const float*)d_in[20];
    const float* mlp_W2 = (const float*)d_in[21];
    const float* mlp_b2 = (const float*)d_in[22];

    const int N  = in_sizes[0] / 128;
    const int E  = in_sizes[1] / 2;
    const int Bn = in_sizes[6];
    const int nblk = (E + EPB - 1) / EPB;
    int bsh = 0;
    while (((size_t)NB << bsh) < (size_t)N) ++bsh;  // bucket width 2^bsh

    char* w = (char*)d_ws;
    auto alloc = [&](size_t bytes) {
        char* p = w;
        w += (bytes + 255) & ~(size_t)255;
        return p;
    };
    char*  bufYraw     = alloc((size_t)N * 64 * sizeof(float));  // bf16 Y + pairs alias
    char*  bufRraw     = alloc((size_t)N * 64 * sizeof(__hip_bfloat16));
    float* bufH        = (float*)alloc((size_t)N * 64 * sizeof(float));
    int*   csr         = (int*)alloc((size_t)2 * E * sizeof(int));
    int*   row_start   = (int*)alloc((size_t)2 * (N + 1) * sizeof(int));
    int*   blkhist     = (int*)alloc((size_t)2 * nblk * NB * sizeof(int));
    int*   basem       = (int*)alloc((size_t)2 * nblk * NB * sizeof(int));
    int*   bucket_base = (int*)alloc((size_t)2 * (NB + 1) * sizeof(int));
    float* partsS      = (float*)alloc((size_t)Bn * PP * 64 * sizeof(float));
    float* partsG      = (float*)alloc((size_t)Bn * PP * 64 * sizeof(float));
    int*   cntS        = (int*)alloc((size_t)Bn * sizeof(int));
    int*   cntG        = (int*)alloc((size_t)Bn * sizeof(int));
    __hip_bfloat16* bufY = (__hip_bfloat16*)bufYraw;
    __hip_bfloat16* bufR = (__hip_bfloat16*)bufRraw;
    int*   pairs       = (int*)bufYraw;  // packed pairs alias bufY (dead in CSR build)
    const size_t need = (size_t)(w - (char*)d_ws);
    const bool pairs_fit = (size_t)2 * E * sizeof(int) <= (size_t)N * 64 * sizeof(float);
    if (need > ws_size || (1 << bsh) > BWMAX || !pairs_fit || N > (1 << SRCB)) {
        hipMemsetAsync(d_out, 0, (size_t)out_size * sizeof(float), stream);
        return;
    }

    // ---- CSR build, both graphs ----
    p1_hist<<<2 * nblk, 256, 0, stream>>>(state_ei + E, goal_ei + E, blkhist, E, bsh, nblk);
    p1_scan<<<2, NB, 0, stream>>>(blkhist, basem, bucket_base, nblk);
    p1_scatter<<<2 * nblk, 256, 0, stream>>>(state_ei, goal_ei, basem, pairs, E, bsh, nblk);
    p2_sort<<<2 * NB, 512, 0, stream>>>(pairs, bucket_base, csr, row_start, N, E, bsh);

    const int g64 = (N + 63) / 64;
    const int g4  = (N + 3) / 4;
    const int* csrS = csr;
    const int* csrG = csr + E;
    const int* rsS  = row_start;
    const int* rsG  = row_start + (N + 1);

    // ---- state encoder ----
    gemm_fused<128><<<g64, 512, 0, stream>>>(state_x, s1_Wl, s1_Wr, bufY, bufR, N);
    agg_fused<<<g4, 256, 0, stream>>>(bufY, bufR, s1_bl, csrS, rsS, bufH, N);
    gemm_fused<64><<<g64, 512, 0, stream>>>(bufH, s2_Wl, s2_Wr, bufY, bufR, N);
    agg_fused<<<g4, 256, 0, stream>>>(bufY, bufR, s2_bl, csrS, rsS, bufH, N);
    pool_part<<<Bn * PP, 256, 0, stream>>>(bufH, state_batch, partsS, cntS, N);

    // ---- goal encoder ----
    gemm_fused<128><<<g64, 512, 0, stream>>>(goal_x, g1_Wl, g1_Wr, bufY, bufR, N);
    agg_fused<<<g4, 256, 0, stream>>>(bufY, bufR, g1_bl, csrG, rsG, bufH, N);
    gemm_fused<64><<<g64, 512, 0, stream>>>(bufH, g2_Wl, g2_Wr, bufY, bufR, N);
    agg_fused<<<g4, 256, 0, stream>>>(bufY, bufR, g2_bl, csrG, rsG, bufH, N);
    pool_part<<<Bn * PP, 256, 0, stream>>>(bufH, goal_batch, partsG, cntG, N);

    final_mlp<<<Bn, 64, 0, stream>>>(partsS, cntS, partsG, cntG, depth,
                                     mlp_W1, mlp_b1, mlp_W2, mlp_b2, (float*)d_out, Bn);
}